// Round 2
// baseline (269.206 us; speedup 1.0000x reference)
//
#include <hip/hip_runtime.h>
#include <math.h>

// Problem constants (fixed by reference setup_inputs)
#define T_TOK 16384
#define DDIM  2048
#define NE    64
#define NPLANE (NE * DDIM)      // 131072 elements per W split plane
#define NBLK  256               // main-kernel grid (64 tokens each)
#define DRING 6                 // LDS ring depth (5-step lookahead)

typedef __attribute__((ext_vector_type(8))) short short8;   // 8 bf16 MFMA frag
typedef __attribute__((ext_vector_type(4))) float floatx4;  // MFMA C/D

union Frag8 { unsigned short u[8]; short8 v; };

__device__ __forceinline__ unsigned int bf16_rne_bits(float x) {
    unsigned int u = __builtin_bit_cast(unsigned int, x);
    return (u + 0x7fffu + ((u >> 16) & 1u)) & 0xffff0000u;
}

// async global->LDS DMA, 16 B per lane; LDS dest = uniform base + lane*16
__device__ __forceinline__ void dma16(const void* g, void* lds) {
    __builtin_amdgcn_global_load_lds(
        (const __attribute__((address_space(1))) unsigned int*)g,
        (__attribute__((address_space(3))) unsigned int*)lds, 16, 0, 0);
}

// ---- pre-kernel: exact 3-way bf16 split of W (fp32 = h + m + l) ----
__global__ void wsplit_kernel(const float* __restrict__ W,
                              unsigned short* __restrict__ wh,
                              unsigned short* __restrict__ wm,
                              unsigned short* __restrict__ wl) {
    int i = blockIdx.x * 256 + threadIdx.x;   // grid covers exactly NPLANE
    float w = W[i];
    unsigned int hb = bf16_rne_bits(w);
    float r  = w - __builtin_bit_cast(float, hb);   // exact
    unsigned int mb = bf16_rne_bits(r);
    float r2 = r - __builtin_bit_cast(float, mb);   // exact
    unsigned int lb = bf16_rne_bits(r2);            // |err| <= 2^-24 |w|
    wh[i] = (unsigned short)(hb >> 16);
    wm[i] = (unsigned short)(mb >> 16);
    wl[i] = (unsigned short)(lb >> 16);
}

// ---- main: 64-token block, DMA ring (depth 6), counted-vmcnt pipeline ----
// Grid 256 = 1 block/CU. Block 512 thr = 8 waves.
// Wave (tg = wv>>1, eh = wv&1): 16 tokens x 32 experts x full 2048 k.
// Per step (BK=32): A chunk 8 KB + B chunk 12 KB staged by global_load_lds
// into ring slot; waves 0-3 issue 3 B-insts, waves 4-7 issue 2 A-insts.
// Loop: s_waitcnt vmcnt(4*own) -> s_barrier -> prefetch step c+5 -> compute.
// LDS: ringA 48 KB + ringB 72 KB + lg 16 KB + ured 2 KB = 138 KB, 1 blk/CU.
__global__ __launch_bounds__(512, 2)
void router_main(const float* __restrict__ x,
                 const unsigned short* __restrict__ whp,
                 const unsigned short* __restrict__ wmp,
                 const unsigned short* __restrict__ wlp,
                 float* __restrict__ out, float* __restrict__ usage_part) {
    __shared__ float          ringA[DRING * 2048];   // slot: [64 tok][32 k] f32, XOR-swz
    __shared__ unsigned short ringB[DRING * 6144];   // slot: [3 p][4 q][64 e][8 k] bf16
    __shared__ float          lg[64 * 64];           // full logits [tok][exp]
    __shared__ float          ured[8][NE];

    const int tid  = threadIdx.x;
    const int lane = tid & 63;
    const int wv   = __builtin_amdgcn_readfirstlane(tid >> 6);  // 0..7
    const int tg   = wv >> 1;    // token group (16 tokens)
    const int eh   = wv & 1;     // expert half (32 experts)
    const int cl   = lane & 15;  // frag row index (token / expert)
    const int q    = lane >> 4;  // frag k-quad
    const int t0   = blockIdx.x * 64;

    // ---- per-lane DMA sources ----
    // A: lane covers row (i*8 + lane>>3), 16B col ((lane&7)*16) ^ ((row&7)<<4)
    const int swcol = ((((lane & 7) * 16) ^ ((lane >> 3) << 4)) >> 2); // float idx
    const int ai    = (wv >= 4) ? (wv - 4) * 2 : 0;                    // A inst base
    const float* asrc0 = x + (size_t)(t0 + ai * 8 + (lane >> 3)) * DDIM + swcol;
    const float* asrc1 = asrc0 + (size_t)8 * DDIM;
    // B: inst (p, q=wv): lane = expert row; 16 B = 8 bf16 at k = kd*32 + wv*8
    const unsigned short* bsrc0 = whp + (size_t)lane * DDIM + wv * 8;
    const unsigned short* bsrc1 = wmp + (size_t)lane * DDIM + wv * 8;
    const unsigned short* bsrc2 = wlp + (size_t)lane * DDIM + wv * 8;

    floatx4 acc[2];
    acc[0] = (floatx4){0.f, 0.f, 0.f, 0.f};
    acc[1] = (floatx4){0.f, 0.f, 0.f, 0.f};

    // ---- prologue: stage steps 0..4 into slots 0..4 ----
#pragma unroll
    for (int s = 0; s < 5; ++s) {
        if (wv < 4) {
            dma16(bsrc0 + s * 32, (void*)(ringB + s * 6144 + 0 * 2048 + wv * 512));
            dma16(bsrc1 + s * 32, (void*)(ringB + s * 6144 + 1 * 2048 + wv * 512));
            dma16(bsrc2 + s * 32, (void*)(ringB + s * 6144 + 2 * 2048 + wv * 512));
        } else {
            dma16(asrc0 + s * 32, (void*)(ringA + s * 2048 + (ai + 0) * 256));
            dma16(asrc1 + s * 32, (void*)(ringA + s * 2048 + (ai + 1) * 256));
        }
    }

    int rs = 0, ws = 5;
#pragma unroll 1
    for (int c = 0; c < 64; ++c) {
        // own step-c DMAs retired (FIFO): outstanding <= 4 * own
        if (wv < 4) { asm volatile("s_waitcnt vmcnt(12)" ::: "memory"); }
        else        { asm volatile("s_waitcnt vmcnt(8)"  ::: "memory"); }
        __builtin_amdgcn_s_barrier();          // publish step c; free slot ws
        __builtin_amdgcn_sched_barrier(0);

        // prefetch step c+5 into freed slot (clamped dummy past the end keeps
        // the counted vmcnt constant; dummy slots are never read)
        {
            int kd = c + 5; if (kd > 63) kd = 63;
            if (wv < 4) {
                dma16(bsrc0 + kd * 32, (void*)(ringB + ws * 6144 + 0 * 2048 + wv * 512));
                dma16(bsrc1 + kd * 32, (void*)(ringB + ws * 6144 + 1 * 2048 + wv * 512));
                dma16(bsrc2 + kd * 32, (void*)(ringB + ws * 6144 + 2 * 2048 + wv * 512));
            } else {
                dma16(asrc0 + kd * 32, (void*)(ringA + ws * 2048 + (ai + 0) * 256));
                dma16(asrc1 + kd * 32, (void*)(ringA + ws * 2048 + (ai + 1) * 256));
            }
        }

        // A frag: token tg*16+cl, k = q*8..+8, from XOR-swizzled slot
        const float* Arow = ringA + rs * 2048 + (tg * 16 + cl) * 32;
        const int x0 = ((q * 32)      ^ ((cl & 7) << 4)) >> 2;
        const int x1 = ((q * 32 + 16) ^ ((cl & 7) << 4)) >> 2;
        float4 a0 = *(const float4*)(Arow + x0);   // k j=0..3
        float4 a1 = *(const float4*)(Arow + x1);   // k j=4..7
        float f[8] = {a0.x, a0.y, a0.z, a0.w, a1.x, a1.y, a1.z, a1.w};
        Frag8 fh, fm, fl;
#pragma unroll
        for (int j = 0; j < 8; ++j) {
            unsigned int ub = __builtin_bit_cast(unsigned int, f[j]);
            unsigned int hb = ub & 0xffff0000u;
            float r = f[j] - __builtin_bit_cast(float, hb);   // exact
            unsigned int rb = __builtin_bit_cast(unsigned int, r);
            unsigned int mb = rb & 0xffff0000u;
            float r2 = r - __builtin_bit_cast(float, mb);     // exact
            unsigned int lb = __builtin_bit_cast(unsigned int, r2);
            fh.u[j] = (unsigned short)(hb >> 16);
            fm.u[j] = (unsigned short)(mb >> 16);
            fl.u[j] = (unsigned short)(lb >> 16);
        }
        short8 Ah = fh.v, Am = fm.v, Al = fl.v;

        // B frags from LDS + 6-pass MFMA (hh+hm+mh+mm+hl+lh)
#pragma unroll
        for (int nt = 0; nt < 2; ++nt) {
            const unsigned short* bp =
                ringB + rs * 6144 + q * 512 + (eh * 32 + nt * 16 + cl) * 8;
            short8 Bh = __builtin_bit_cast(short8, *(const uint4*)(bp));
            short8 Bm = __builtin_bit_cast(short8, *(const uint4*)(bp + 2048));
            short8 Bl = __builtin_bit_cast(short8, *(const uint4*)(bp + 4096));
            floatx4 a = acc[nt];
            a = __builtin_amdgcn_mfma_f32_16x16x32_bf16(Ah, Bh, a, 0, 0, 0);
            a = __builtin_amdgcn_mfma_f32_16x16x32_bf16(Ah, Bm, a, 0, 0, 0);
            a = __builtin_amdgcn_mfma_f32_16x16x32_bf16(Am, Bh, a, 0, 0, 0);
            a = __builtin_amdgcn_mfma_f32_16x16x32_bf16(Am, Bm, a, 0, 0, 0);
            a = __builtin_amdgcn_mfma_f32_16x16x32_bf16(Ah, Bl, a, 0, 0, 0);
            a = __builtin_amdgcn_mfma_f32_16x16x32_bf16(Al, Bh, a, 0, 0, 0);
            acc[nt] = a;
        }

        rs = (rs == DRING - 1) ? 0 : rs + 1;
        ws = (ws == DRING - 1) ? 0 : ws + 1;
    }

    // full-k logits -> lg. D layout: n(expert)=lane&15, m(token)=q*4+reg
#pragma unroll
    for (int nt = 0; nt < 2; ++nt)
#pragma unroll
        for (int r = 0; r < 4; ++r)
            lg[(tg * 16 + q * 4 + r) * 64 + eh * 32 + nt * 16 + cl] = acc[nt][r];
    __syncthreads();   // also drains dangling dummy DMAs (compiler vmcnt(0))

    // ---- epilogue (verified structure): lane = expert, 8 tokens/wave ----
    float usage_acc = 0.f;
#pragma unroll 1
    for (int j = 0; j < 8; ++j) {
        const int tl = wv * 8 + j;
        const int t  = t0 + tl;
        float l = lg[tl * 64 + lane];

        float v1 = l; int i1 = lane;
#pragma unroll
        for (int off = 32; off >= 1; off >>= 1) {
            float ov = __shfl_xor(v1, off, 64);
            int   oi = __shfl_xor(i1, off, 64);
            if (ov > v1 || (ov == v1 && oi < i1)) { v1 = ov; i1 = oi; }
        }
        float lm = (lane == i1) ? -INFINITY : l;
        float v2 = lm; int i2 = lane;
#pragma unroll
        for (int off = 32; off >= 1; off >>= 1) {
            float ov = __shfl_xor(v2, off, 64);
            int   oi = __shfl_xor(i2, off, 64);
            if (ov > v2 || (ov == v2 && oi < i2)) { v2 = ov; i2 = oi; }
        }

        float p = expf(l - v1);
        float s = p;
#pragma unroll
        for (int off = 32; off >= 1; off >>= 1) s += __shfl_xor(s, off, 64);

        float e2  = expf(v2 - v1);
        float rcp = 1.0f / (1.0f + e2);
        usage_acc += p / s;

        if (lane == 0) {
            out[(size_t)t * 2 + 0]         = (float)i1;
            out[(size_t)t * 2 + 1]         = (float)i2;
            out[32768 + (size_t)t * 2 + 0] = rcp;
            out[32768 + (size_t)t * 2 + 1] = e2 * rcp;
        }
    }

    // per-block usage partials (no atomics; deterministic)
    ured[wv][lane] = usage_acc;
    __syncthreads();
    if (wv == 0) {
        float s = ((ured[0][lane] + ured[1][lane]) + (ured[2][lane] + ured[3][lane])) +
                  ((ured[4][lane] + ured[5][lane]) + (ured[6][lane] + ured[7][lane]));
        usage_part[(size_t)blockIdx.x * 64 + lane] = s;
    }
}

__global__ __launch_bounds__(1024)
void router_aux(const float* __restrict__ usage_part, float* __restrict__ out) {
    __shared__ float red[16][NE];
    const int tid = threadIdx.x;    // 1024
    const int e   = tid & 63;
    const int g   = tid >> 6;       // 0..15
    float s = 0.f;
#pragma unroll
    for (int i = 0; i < NBLK / 16; ++i)
        s += usage_part[(size_t)(g * (NBLK / 16) + i) * 64 + e];
    red[g][e] = s;
    __syncthreads();
    if (g == 0) {
        float tot = 0.f;
#pragma unroll
        for (int i = 0; i < 16; ++i) tot += red[i][e];
        float u = tot * (1.0f / 16384.0f) - (1.0f / 64.0f);
        float sq = u * u;
#pragma unroll
        for (int off = 32; off >= 1; off >>= 1) sq += __shfl_xor(sq, off, 64);
        if (e == 0) out[65536] = sq;
    }
}

extern "C" void kernel_launch(void* const* d_in, const int* in_sizes, int n_in,
                              void* d_out, int out_size, void* d_ws, size_t ws_size,
                              hipStream_t stream) {
    const float* x = (const float*)d_in[0];   // [4,4096,2048] fp32
    const float* W = (const float*)d_in[1];   // [64,2048] fp32
    float* out     = (float*)d_out;           // 65537 floats

    // ws layout: Wh | Wm | Wl (bf16 planes, 256 KB each) | usage partials (64 KB)
    unsigned short* ws_h = (unsigned short*)d_ws;
    unsigned short* ws_m = ws_h + NPLANE;
    unsigned short* ws_l = ws_m + NPLANE;
    float* upart         = (float*)(ws_l + NPLANE);

    wsplit_kernel<<<dim3(NPLANE / 256), dim3(256), 0, stream>>>(W, ws_h, ws_m, ws_l);
    router_main<<<dim3(NBLK), dim3(512), 0, stream>>>(x, ws_h, ws_m, ws_l, out, upart);
    router_aux<<<dim3(1), dim3(1024), 0, stream>>>(upart, out);
}

// Round 3
// 240.239 us; speedup vs baseline: 1.1206x; 1.1206x over previous
//
#include <hip/hip_runtime.h>
#include <math.h>

// Problem constants (fixed by reference setup_inputs)
#define T_TOK 16384
#define DDIM  2048
#define NE    64
#define NPLANE (NE * DDIM)      // 131072 elements per W split plane
#define NBLK  512               // main-kernel grid (32 tokens each)

typedef __attribute__((ext_vector_type(8))) short short8;   // 8 bf16 MFMA frag
typedef __attribute__((ext_vector_type(4))) float floatx4;  // MFMA C/D

union Frag8 { unsigned short u[8]; short8 v; };

__device__ __forceinline__ unsigned int bf16_rne_bits(float x) {
    unsigned int u = __builtin_bit_cast(unsigned int, x);
    return (u + 0x7fffu + ((u >> 16) & 1u)) & 0xffff0000u;
}

// async global->LDS DMA, 16 B per lane; LDS dest = uniform base + lane*16
__device__ __forceinline__ void dma16(const float* g, float* lds) {
    __builtin_amdgcn_global_load_lds(
        (const __attribute__((address_space(1))) unsigned int*)g,
        (__attribute__((address_space(3))) unsigned int*)lds, 16, 0, 0);
}

// ---- pre-kernel: exact 3-way bf16 split of W (fp32 = h + m + l) ----
__global__ void wsplit_kernel(const float* __restrict__ W,
                              unsigned short* __restrict__ wh,
                              unsigned short* __restrict__ wm,
                              unsigned short* __restrict__ wl) {
    int i = blockIdx.x * 256 + threadIdx.x;   // grid covers exactly NPLANE
    float w = W[i];
    unsigned int hb = bf16_rne_bits(w);
    float r  = w - __builtin_bit_cast(float, hb);   // exact
    unsigned int mb = bf16_rne_bits(r);
    float r2 = r - __builtin_bit_cast(float, mb);   // exact
    unsigned int lb = bf16_rne_bits(r2);            // |err| <= 2^-24 |w|
    wh[i] = (unsigned short)(hb >> 16);
    wm[i] = (unsigned short)(mb >> 16);
    wl[i] = (unsigned short)(lb >> 16);
}

// ---- main: R0 structure at 2x TLP. 1024 thr = 16 waves = nh(2) x kq(8).
// Wave tile: 32 tokens x 32 experts x 256 k. Chunk = 32 k per kq (32 KB buf),
// double-buffered DMA staging exactly as R0. 2 blocks/CU x 16 waves = 32
// waves/CU (100% occupancy) vs R0's 16.
// LDS: As[2][8192] f32 (64 KB); lg[8][32][64] overlays BOTH buffers after the
// post-loop barrier; ured separate 4 KB. Total 69.6 KB -> 2 blk/CU.
__global__ __launch_bounds__(1024, 8)
void router_main(const float* __restrict__ x,
                 const unsigned short* __restrict__ wh,
                 const unsigned short* __restrict__ wm,
                 const unsigned short* __restrict__ wl,
                 float* __restrict__ out, float* __restrict__ usage_part) {
    __shared__ float As[2 * 8192];     // 64 KB staging; lg overlays after loop
    __shared__ float ured[16][NE];     // 4 KB
    float* lg = As;                    // [8][32][64] overlay (written post-loop)

    const int tid  = threadIdx.x;
    const int lane = tid & 63;
    const int wv   = __builtin_amdgcn_readfirstlane(tid >> 6);  // 0..15
    const int nh   = wv & 1;     // expert half (32 experts)
    const int kq   = wv >> 1;    // k eighth   (256 k)
    const int cl   = lane & 15;  // frag row index (token / expert)
    const int q    = lane >> 4;  // frag k-quad
    const int t0   = blockIdx.x * 32;

    // DMA lane role (token-major, R0-proven layout [k8-group][j-half][tok][4]):
    // lane l stages token (l&31), float4-half (l>>5); wave covers k8-groups
    // g = nh*2 + {0,1} of its kq chunk.
    const float* xdma = x + (size_t)(t0 + (lane & 31)) * DDIM + kq * 256 + (lane >> 5) * 4;

    floatx4 acc[2][2];
#pragma unroll
    for (int mt = 0; mt < 2; ++mt)
#pragma unroll
        for (int nt = 0; nt < 2; ++nt)
            acc[mt][nt] = (floatx4){0.f, 0.f, 0.f, 0.f};

    const size_t bbase = (size_t)(nh * 32 + cl) * DDIM + kq * 256 + q * 8;

    // prologue: DMA chunk 0 -> buffer 0 (2 insts/wave)
#pragma unroll
    for (int g2 = 0; g2 < 2; ++g2) {
        const int g = nh * 2 + g2;
        dma16(xdma + g * 8, As + kq * 1024 + g * 256);
    }

#pragma unroll 1
    for (int c = 0; c < 8; ++c) {
        __syncthreads();   // drains DMA(c); also frees buf[(c+1)&1] for prefetch

        if (c + 1 < 8) {   // prefetch next chunk into alternate buffer
            float* nb = As + ((c + 1) & 1) * 8192 + kq * 1024;
#pragma unroll
            for (int g2 = 0; g2 < 2; ++g2) {
                const int g = nh * 2 + g2;
                dma16(xdma + (c + 1) * 32 + g * 8, nb + g * 256);
            }
        }

        const float* buf = As + (c & 1) * 8192 + kq * 1024;

        // B frags (L2-resident split planes), k = kq*256 + c*32 + q*8
        const size_t bo = bbase + c * 32;
        uint4 cb[2][3];
#pragma unroll
        for (int nt = 0; nt < 2; ++nt) {
            const size_t o = bo + (size_t)nt * 16 * DDIM;
            cb[nt][0] = *(const uint4*)(wh + o);
            cb[nt][1] = *(const uint4*)(wm + o);
            cb[nt][2] = *(const uint4*)(wl + o);
        }
        // A frags from LDS + truncation 3-way split (exact residuals)
        short8 Ah[2], Am[2], Al[2];
#pragma unroll
        for (int mt = 0; mt < 2; ++mt) {
            const float* ap = buf + q * 256 + (mt * 16 + cl) * 4;
            float4 a0 = *(const float4*)(ap);        // k j=0..3
            float4 a1 = *(const float4*)(ap + 128);  // k j=4..7
            float f[8] = {a0.x, a0.y, a0.z, a0.w, a1.x, a1.y, a1.z, a1.w};
            Frag8 fh, fm, fl;
#pragma unroll
            for (int j = 0; j < 8; ++j) {
                unsigned int ub = __builtin_bit_cast(unsigned int, f[j]);
                unsigned int hb = ub & 0xffff0000u;
                float r = f[j] - __builtin_bit_cast(float, hb);   // exact
                unsigned int rb = __builtin_bit_cast(unsigned int, r);
                unsigned int mb = rb & 0xffff0000u;
                float r2 = r - __builtin_bit_cast(float, mb);     // exact
                unsigned int lb = __builtin_bit_cast(unsigned int, r2);
                fh.u[j] = (unsigned short)(hb >> 16);
                fm.u[j] = (unsigned short)(mb >> 16);
                fl.u[j] = (unsigned short)(lb >> 16);
            }
            Ah[mt] = fh.v; Am[mt] = fm.v; Al[mt] = fl.v;
        }

        // 6 passes: hh + hm + mh + mm + hl + lh
#pragma unroll
        for (int mt = 0; mt < 2; ++mt)
#pragma unroll
            for (int nt = 0; nt < 2; ++nt) {
                short8 Bh = __builtin_bit_cast(short8, cb[nt][0]);
                short8 Bm = __builtin_bit_cast(short8, cb[nt][1]);
                short8 Bl = __builtin_bit_cast(short8, cb[nt][2]);
                floatx4 a = acc[mt][nt];
                a = __builtin_amdgcn_mfma_f32_16x16x32_bf16(Ah[mt], Bh, a, 0, 0, 0);
                a = __builtin_amdgcn_mfma_f32_16x16x32_bf16(Ah[mt], Bm, a, 0, 0, 0);
                a = __builtin_amdgcn_mfma_f32_16x16x32_bf16(Am[mt], Bh, a, 0, 0, 0);
                a = __builtin_amdgcn_mfma_f32_16x16x32_bf16(Am[mt], Bm, a, 0, 0, 0);
                a = __builtin_amdgcn_mfma_f32_16x16x32_bf16(Ah[mt], Bl, a, 0, 0, 0);
                a = __builtin_amdgcn_mfma_f32_16x16x32_bf16(Al[mt], Bh, a, 0, 0, 0);
                acc[mt][nt] = a;
            }
    }

    __syncthreads();   // all waves done reading As -> safe to overlay lg

    // partial logits -> lg. D layout: n(expert) = lane&15, m(token) = q*4+reg
#pragma unroll
    for (int mt = 0; mt < 2; ++mt)
#pragma unroll
        for (int nt = 0; nt < 2; ++nt)
#pragma unroll
            for (int r = 0; r < 4; ++r)
                lg[kq * 2048 + (mt * 16 + q * 4 + r) * 64 + nh * 32 + nt * 16 + cl]
                    = acc[mt][nt][r];
    __syncthreads();

    // ---- epilogue (verified rounds 0-1): lane = expert, 2 tokens/wave ----
    float usage_acc = 0.f;
#pragma unroll 1
    for (int j = 0; j < 2; ++j) {
        const int tl = wv * 2 + j;
        const int t  = t0 + tl;
        // R1's verified 8-partial pairwise tree (absmax 0.0)
        float l = (((lg[0 * 2048 + tl * 64 + lane] + lg[1 * 2048 + tl * 64 + lane]) +
                    (lg[2 * 2048 + tl * 64 + lane] + lg[3 * 2048 + tl * 64 + lane])) +
                   ((lg[4 * 2048 + tl * 64 + lane] + lg[5 * 2048 + tl * 64 + lane]) +
                    (lg[6 * 2048 + tl * 64 + lane] + lg[7 * 2048 + tl * 64 + lane])));

        float v1 = l; int i1 = lane;
#pragma unroll
        for (int off = 32; off >= 1; off >>= 1) {
            float ov = __shfl_xor(v1, off, 64);
            int   oi = __shfl_xor(i1, off, 64);
            if (ov > v1 || (ov == v1 && oi < i1)) { v1 = ov; i1 = oi; }
        }
        float lm = (lane == i1) ? -INFINITY : l;
        float v2 = lm; int i2 = lane;
#pragma unroll
        for (int off = 32; off >= 1; off >>= 1) {
            float ov = __shfl_xor(v2, off, 64);
            int   oi = __shfl_xor(i2, off, 64);
            if (ov > v2 || (ov == v2 && oi < i2)) { v2 = ov; i2 = oi; }
        }

        float p = expf(l - v1);
        float s = p;
#pragma unroll
        for (int off = 32; off >= 1; off >>= 1) s += __shfl_xor(s, off, 64);

        float e2  = expf(v2 - v1);
        float rcp = 1.0f / (1.0f + e2);
        usage_acc += p / s;

        if (lane == 0) {
            out[(size_t)t * 2 + 0]         = (float)i1;
            out[(size_t)t * 2 + 1]         = (float)i2;
            out[32768 + (size_t)t * 2 + 0] = rcp;
            out[32768 + (size_t)t * 2 + 1] = e2 * rcp;
        }
    }

    // per-block usage partials (no atomics; deterministic)
    ured[wv][lane] = usage_acc;
    __syncthreads();
    if (wv == 0) {
        float s = (((ured[0][lane] + ured[1][lane]) + (ured[2][lane] + ured[3][lane])) +
                   ((ured[4][lane] + ured[5][lane]) + (ured[6][lane] + ured[7][lane]))) +
                  (((ured[8][lane] + ured[9][lane]) + (ured[10][lane] + ured[11][lane])) +
                   ((ured[12][lane] + ured[13][lane]) + (ured[14][lane] + ured[15][lane])));
        usage_part[(size_t)blockIdx.x * 64 + lane] = s;
    }
}

__global__ __launch_bounds__(1024)
void router_aux(const float* __restrict__ usage_part, float* __restrict__ out) {
    __shared__ float red[16][NE];
    const int tid = threadIdx.x;    // 1024
    const int e   = tid & 63;
    const int g   = tid >> 6;       // 0..15
    float s = 0.f;
#pragma unroll
    for (int i = 0; i < NBLK / 16; ++i)
        s += usage_part[(size_t)(g * (NBLK / 16) + i) * 64 + e];
    red[g][e] = s;
    __syncthreads();
    if (g == 0) {
        float tot = 0.f;
#pragma unroll
        for (int i = 0; i < 16; ++i) tot += red[i][e];
        float u = tot * (1.0f / 16384.0f) - (1.0f / 64.0f);
        float sq = u * u;
#pragma unroll
        for (int off = 32; off >= 1; off >>= 1) sq += __shfl_xor(sq, off, 64);
        if (e == 0) out[65536] = sq;
    }
}

extern "C" void kernel_launch(void* const* d_in, const int* in_sizes, int n_in,
                              void* d_out, int out_size, void* d_ws, size_t ws_size,
                              hipStream_t stream) {
    const float* x = (const float*)d_in[0];   // [4,4096,2048] fp32
    const float* W = (const float*)d_in[1];   // [64,2048] fp32
    float* out     = (float*)d_out;           // 65537 floats

    // ws layout: Wh | Wm | Wl (bf16 planes, 256 KB each) | usage partials (128 KB)
    unsigned short* ws_h = (unsigned short*)d_ws;
    unsigned short* ws_m = ws_h + NPLANE;
    unsigned short* ws_l = ws_m + NPLANE;
    float* upart         = (float*)(ws_l + NPLANE);

    wsplit_kernel<<<dim3(NPLANE / 256), dim3(256), 0, stream>>>(W, ws_h, ws_m, ws_l);
    router_main<<<dim3(NBLK), dim3(1024), 0, stream>>>(x, ws_h, ws_m, ws_l, out, upart);
    router_aux<<<dim3(1), dim3(1024), 0, stream>>>(upart, out);
}

// Round 4
// 232.585 us; speedup vs baseline: 1.1575x; 1.0329x over previous
//
#include <hip/hip_runtime.h>
#include <math.h>

// Problem constants (fixed by reference setup_inputs)
#define T_TOK 16384
#define DDIM  2048
#define NE    64
#define NPLANE (NE * DDIM)      // 131072 elements per W split plane
#define NBLK  512               // main-kernel grid (32 tokens each)

typedef __attribute__((ext_vector_type(8))) short short8;   // 8 bf16 MFMA frag
typedef __attribute__((ext_vector_type(4))) float floatx4;  // MFMA C/D

union Frag8 { unsigned short u[8]; short8 v; };

__device__ __forceinline__ unsigned int bf16_rne_bits(float x) {
    unsigned int u = __builtin_bit_cast(unsigned int, x);
    return (u + 0x7fffu + ((u >> 16) & 1u)) & 0xffff0000u;
}

// async global->LDS DMA, 16 B per lane; LDS dest = uniform base + lane*16
__device__ __forceinline__ void dma16(const float* g, float* lds) {
    __builtin_amdgcn_global_load_lds(
        (const __attribute__((address_space(1))) unsigned int*)g,
        (__attribute__((address_space(3))) unsigned int*)lds, 16, 0, 0);
}

// ---- pre-kernel: exact 3-way bf16 split of W, PACKED in MFMA-frag order ----
// packed idx = ((kc*4 + et)*4 + q)*128 + cl*8 + j
//   expert e = et*16 + cl,  k = kc*32 + q*8 + j
// => a wave's B-frag load (fixed p, kc, et; lanes (q,cl)) is 1 KB contiguous.
__global__ void wsplit_kernel(const float* __restrict__ W,
                              unsigned short* __restrict__ wh,
                              unsigned short* __restrict__ wm,
                              unsigned short* __restrict__ wl) {
    int i  = blockIdx.x * 256 + threadIdx.x;   // grid covers exactly NPLANE
    int j  = i & 7;
    int cl = (i >> 3) & 15;
    int q  = (i >> 7) & 3;
    int et = (i >> 9) & 3;
    int kc = i >> 11;                          // 0..63
    int e  = et * 16 + cl;
    int k  = kc * 32 + q * 8 + j;
    float w = W[e * DDIM + k];
    unsigned int hb = bf16_rne_bits(w);
    float r  = w - __builtin_bit_cast(float, hb);   // exact
    unsigned int mb = bf16_rne_bits(r);
    float r2 = r - __builtin_bit_cast(float, mb);   // exact
    unsigned int lb = bf16_rne_bits(r2);            // |err| <= 2^-24 |w|
    wh[i] = (unsigned short)(hb >> 16);
    wm[i] = (unsigned short)(mb >> 16);
    wl[i] = (unsigned short)(lb >> 16);
}

// ---- main: R3 shell (1024 thr = 16 waves = nh(2) x kq(8), 2 blk/CU) with
// sequential memory patterns.
// Phase c stages x k-window [c*256, c*256+256) for all 32 tokens: 32 DMA
// insts, each 1 KB CONTIGUOUS of one token row (16-B chunks XOR-swizzled by
// tok&7 on the SOURCE side; LDS stays linear per rule #21).
// Wave (nh,kq) consumes k = c*256 + kq*32 + q*8 (global k-chunk kc = c*8+kq).
// B frags: 1 KB contiguous loads from the packed planes (values bitwise
// identical to R0-R3's strided loads).
// LDS: As[2][8192] f32 (64 KB, lg overlays after loop) + ured 4 KB.
__global__ __launch_bounds__(1024, 8)
void router_main(const float* __restrict__ x,
                 const unsigned short* __restrict__ wh,
                 const unsigned short* __restrict__ wm,
                 const unsigned short* __restrict__ wl,
                 float* __restrict__ out, float* __restrict__ usage_part) {
    __shared__ float As[2 * 8192];     // 64 KB staging; lg overlays after loop
    __shared__ float ured[16][NE];     // 4 KB
    float* lg = As;                    // [8][32][64] overlay (written post-loop)

    const int tid  = threadIdx.x;
    const int lane = tid & 63;
    const int wv   = __builtin_amdgcn_readfirstlane(tid >> 6);  // 0..15
    const int nh   = wv & 1;     // expert half (32 experts)
    const int kq   = wv >> 1;    // k sub-slice within each 256-k window
    const int cl   = lane & 15;  // frag row index (token / expert)
    const int q    = lane >> 4;  // frag k-quad
    const int t0   = blockIdx.x * 32;

    // A-DMA role: wave stages local tokens 2wv, 2wv+1. Lane l fetches 16-B
    // chunk (l ^ (tl&7)) of the 256-float window -> LDS linear [tl][l*16B].
    const int tlA0 = 2 * wv, tlA1 = 2 * wv + 1;
    const float* ax0 = x + (size_t)(t0 + tlA0) * DDIM + ((lane ^ (tlA0 & 7)) << 2);
    const float* ax1 = x + (size_t)(t0 + tlA1) * DDIM + ((lane ^ (tlA1 & 7)) << 2);

    floatx4 acc[2][2];
#pragma unroll
    for (int mt = 0; mt < 2; ++mt)
#pragma unroll
        for (int nt = 0; nt < 2; ++nt)
            acc[mt][nt] = (floatx4){0.f, 0.f, 0.f, 0.f};

    // B frag element offsets (phase c adds c*16384):
    //   ((c*8 + kq)*4 + (nh*2+nt))*512 + (q*16+cl)*8
    const unsigned lofs   = (unsigned)((q * 16 + cl) << 3);
    const unsigned bfrag0 = ((unsigned)(kq * 4 + nh * 2 + 0) << 9) + lofs;
    const unsigned bfrag1 = ((unsigned)(kq * 4 + nh * 2 + 1) << 9) + lofs;

    // prologue: DMA phase 0 -> buffer 0
    dma16(ax0, As + tlA0 * 256);
    dma16(ax1, As + tlA1 * 256);

#pragma unroll 1
    for (int c = 0; c < 8; ++c) {
        __syncthreads();   // drains DMA(c); also frees buf[(c+1)&1] for prefetch

        if (c + 1 < 8) {   // prefetch next 256-k window into alternate buffer
            float* nb = As + ((c + 1) & 1) * 8192;
            dma16(ax0 + (c + 1) * 256, nb + tlA0 * 256);
            dma16(ax1 + (c + 1) * 256, nb + tlA1 * 256);
        }

        // B frags: two 1-KB contiguous loads x 3 planes
        const unsigned bo = (unsigned)c * 16384u;
        uint4 cb[2][3];
        {
            const unsigned o0 = bo + bfrag0, o1 = bo + bfrag1;
            cb[0][0] = *(const uint4*)(wh + o0);
            cb[0][1] = *(const uint4*)(wm + o0);
            cb[0][2] = *(const uint4*)(wl + o0);
            cb[1][0] = *(const uint4*)(wh + o1);
            cb[1][1] = *(const uint4*)(wm + o1);
            cb[1][2] = *(const uint4*)(wl + o1);
        }

        // A frags from LDS (chunk-XOR by cl&7) + truncation 3-way split
        const float* buf = As + (c & 1) * 8192;
        const int h0 = (kq * 8 + q * 2) ^ (cl & 7);   // swizzled 16-B chunk idx
        short8 Ah[2], Am[2], Al[2];
#pragma unroll
        for (int mt = 0; mt < 2; ++mt) {
            const float* ap = buf + (mt * 16 + cl) * 256;
            float4 a0 = *(const float4*)(ap + h0 * 4);         // k j=0..3
            float4 a1 = *(const float4*)(ap + (h0 ^ 1) * 4);   // k j=4..7
            float f[8] = {a0.x, a0.y, a0.z, a0.w, a1.x, a1.y, a1.z, a1.w};
            Frag8 fh, fm, fl;
#pragma unroll
            for (int j = 0; j < 8; ++j) {
                unsigned int ub = __builtin_bit_cast(unsigned int, f[j]);
                unsigned int hb = ub & 0xffff0000u;
                float r = f[j] - __builtin_bit_cast(float, hb);   // exact
                unsigned int rb = __builtin_bit_cast(unsigned int, r);
                unsigned int mb = rb & 0xffff0000u;
                float r2 = r - __builtin_bit_cast(float, mb);     // exact
                unsigned int lb = __builtin_bit_cast(unsigned int, r2);
                fh.u[j] = (unsigned short)(hb >> 16);
                fm.u[j] = (unsigned short)(mb >> 16);
                fl.u[j] = (unsigned short)(lb >> 16);
            }
            Ah[mt] = fh.v; Am[mt] = fm.v; Al[mt] = fl.v;
        }

        // 6 passes: hh + hm + mh + mm + hl + lh
#pragma unroll
        for (int mt = 0; mt < 2; ++mt)
#pragma unroll
            for (int nt = 0; nt < 2; ++nt) {
                short8 Bh = __builtin_bit_cast(short8, cb[nt][0]);
                short8 Bm = __builtin_bit_cast(short8, cb[nt][1]);
                short8 Bl = __builtin_bit_cast(short8, cb[nt][2]);
                floatx4 a = acc[mt][nt];
                a = __builtin_amdgcn_mfma_f32_16x16x32_bf16(Ah[mt], Bh, a, 0, 0, 0);
                a = __builtin_amdgcn_mfma_f32_16x16x32_bf16(Ah[mt], Bm, a, 0, 0, 0);
                a = __builtin_amdgcn_mfma_f32_16x16x32_bf16(Am[mt], Bh, a, 0, 0, 0);
                a = __builtin_amdgcn_mfma_f32_16x16x32_bf16(Am[mt], Bm, a, 0, 0, 0);
                a = __builtin_amdgcn_mfma_f32_16x16x32_bf16(Ah[mt], Bl, a, 0, 0, 0);
                a = __builtin_amdgcn_mfma_f32_16x16x32_bf16(Al[mt], Bh, a, 0, 0, 0);
                acc[mt][nt] = a;
            }
    }

    __syncthreads();   // all waves done reading As -> safe to overlay lg

    // partial logits -> lg. D layout: n(expert) = lane&15, m(token) = q*4+reg
#pragma unroll
    for (int mt = 0; mt < 2; ++mt)
#pragma unroll
        for (int nt = 0; nt < 2; ++nt)
#pragma unroll
            for (int r = 0; r < 4; ++r)
                lg[kq * 2048 + (mt * 16 + q * 4 + r) * 64 + nh * 32 + nt * 16 + cl]
                    = acc[mt][nt][r];
    __syncthreads();

    // ---- epilogue (verified rounds 0-3): lane = expert, 2 tokens/wave ----
    float usage_acc = 0.f;
#pragma unroll 1
    for (int j = 0; j < 2; ++j) {
        const int tl = wv * 2 + j;
        const int t  = t0 + tl;
        float l = (((lg[0 * 2048 + tl * 64 + lane] + lg[1 * 2048 + tl * 64 + lane]) +
                    (lg[2 * 2048 + tl * 64 + lane] + lg[3 * 2048 + tl * 64 + lane])) +
                   ((lg[4 * 2048 + tl * 64 + lane] + lg[5 * 2048 + tl * 64 + lane]) +
                    (lg[6 * 2048 + tl * 64 + lane] + lg[7 * 2048 + tl * 64 + lane])));

        float v1 = l; int i1 = lane;
#pragma unroll
        for (int off = 32; off >= 1; off >>= 1) {
            float ov = __shfl_xor(v1, off, 64);
            int   oi = __shfl_xor(i1, off, 64);
            if (ov > v1 || (ov == v1 && oi < i1)) { v1 = ov; i1 = oi; }
        }
        float lm = (lane == i1) ? -INFINITY : l;
        float v2 = lm; int i2 = lane;
#pragma unroll
        for (int off = 32; off >= 1; off >>= 1) {
            float ov = __shfl_xor(v2, off, 64);
            int   oi = __shfl_xor(i2, off, 64);
            if (ov > v2 || (ov == v2 && oi < i2)) { v2 = ov; i2 = oi; }
        }

        float p = expf(l - v1);
        float s = p;
#pragma unroll
        for (int off = 32; off >= 1; off >>= 1) s += __shfl_xor(s, off, 64);

        float e2  = expf(v2 - v1);
        float rcp = 1.0f / (1.0f + e2);
        usage_acc += p / s;

        if (lane == 0) {
            out[(size_t)t * 2 + 0]         = (float)i1;
            out[(size_t)t * 2 + 1]         = (float)i2;
            out[32768 + (size_t)t * 2 + 0] = rcp;
            out[32768 + (size_t)t * 2 + 1] = e2 * rcp;
        }
    }

    // per-block usage partials (no atomics; deterministic)
    ured[wv][lane] = usage_acc;
    __syncthreads();
    if (wv == 0) {
        float s = (((ured[0][lane] + ured[1][lane]) + (ured[2][lane] + ured[3][lane])) +
                   ((ured[4][lane] + ured[5][lane]) + (ured[6][lane] + ured[7][lane]))) +
                  (((ured[8][lane] + ured[9][lane]) + (ured[10][lane] + ured[11][lane])) +
                   ((ured[12][lane] + ured[13][lane]) + (ured[14][lane] + ured[15][lane])));
        usage_part[(size_t)blockIdx.x * 64 + lane] = s;
    }
}

__global__ __launch_bounds__(1024)
void router_aux(const float* __restrict__ usage_part, float* __restrict__ out) {
    __shared__ float red[16][NE];
    const int tid = threadIdx.x;    // 1024
    const int e   = tid & 63;
    const int g   = tid >> 6;       // 0..15
    float s = 0.f;
#pragma unroll
    for (int i = 0; i < NBLK / 16; ++i)
        s += usage_part[(size_t)(g * (NBLK / 16) + i) * 64 + e];
    red[g][e] = s;
    __syncthreads();
    if (g == 0) {
        float tot = 0.f;
#pragma unroll
        for (int i = 0; i < 16; ++i) tot += red[i][e];
        float u = tot * (1.0f / 16384.0f) - (1.0f / 64.0f);
        float sq = u * u;
#pragma unroll
        for (int off = 32; off >= 1; off >>= 1) sq += __shfl_xor(sq, off, 64);
        if (e == 0) out[65536] = sq;
    }
}

extern "C" void kernel_launch(void* const* d_in, const int* in_sizes, int n_in,
                              void* d_out, int out_size, void* d_ws, size_t ws_size,
                              hipStream_t stream) {
    const float* x = (const float*)d_in[0];   // [4,4096,2048] fp32
    const float* W = (const float*)d_in[1];   // [64,2048] fp32
    float* out     = (float*)d_out;           // 65537 floats

    // ws layout: Wh | Wm | Wl (packed bf16 planes, 256 KB each) | usage partials
    unsigned short* ws_h = (unsigned short*)d_ws;
    unsigned short* ws_m = ws_h + NPLANE;
    unsigned short* ws_l = ws_m + NPLANE;
    float* upart         = (float*)(ws_l + NPLANE);

    wsplit_kernel<<<dim3(NPLANE / 256), dim3(256), 0, stream>>>(W, ws_h, ws_m, ws_l);
    router_main<<<dim3(NBLK), dim3(1024), 0, stream>>>(x, ws_h, ws_m, ws_l, out, upart);
    router_aux<<<dim3(1), dim3(1024), 0, stream>>>(upart, out);
}